// Round 7
// baseline (364.318 us; speedup 1.0000x reference)
//
#include <hip/hip_runtime.h>
#include <hip/hip_bf16.h>

#define DF 128

// flagI: 1 = edge_index stored as int64, 0 = int32
// flagD: 1 = x/W/b/out are bf16, 0 = fp32   (round-5/6 evidence: fp32 on this bench)
//
// Hop state is g = dinv .* h (bf16 rows). Then:
//   g_{k+1}[i] = dinv[i]^2 * (g_k[i] + sum_{s in N(i)} g_k[s])
//   h_3[i]     = dinv[i]   * (g_2[i] + sum_s g_2[s])        (last hop)
// -> csr needs only the 4B src index (no per-edge weight), killing the
//    round-6 scatter write-amplification (54MB WRITE_SIZE for 6.4MB payload).

typedef __attribute__((ext_vector_type(8))) short shortx8;   // MFMA A/B frag (8 bf16)
typedef __attribute__((ext_vector_type(4))) float floatx4;   // MFMA C/D frag

__device__ __forceinline__ unsigned short f32_to_bf16_rne(float f) {
    unsigned int u = __float_as_uint(f);
    unsigned int r = (u >> 16) & 1u;
    u += 0x7FFFu + r;
    return (unsigned short)(u >> 16);
}
__device__ __forceinline__ float bf16_lo(unsigned int w) { return __uint_as_float(w << 16); }
__device__ __forceinline__ float bf16_hi(unsigned int w) { return __uint_as_float(w & 0xffff0000u); }
__device__ __forceinline__ unsigned int pack_bf16(float x, float y) {
    return ((unsigned int)f32_to_bf16_rne(y) << 16) | (unsigned int)f32_to_bf16_rne(x);
}

// ---------------- dtype detection ----------------
__global__ void detect_flags_kernel(const unsigned int* __restrict__ ew, int enwords,
                                    const unsigned short* __restrict__ xh, int xnh,
                                    int* __restrict__ flagI, int* __restrict__ flagD) {
    __shared__ int eodd_nz;
    __shared__ int xbig;
    if (threadIdx.x == 0) { eodd_nz = 0; xbig = 0; }
    __syncthreads();
    int f1 = 0;
    for (int i = 1 + 2 * (int)threadIdx.x; i < enwords; i += 2 * (int)blockDim.x)
        if (ew[i] != 0u) f1 = 1;
    int c = 0;
    for (int i = 2 * (int)threadIdx.x; i < xnh; i += 2 * (int)blockDim.x) {
        unsigned int e = ((unsigned int)xh[i] >> 7) & 0xFFu;
        if (e >= 0xC0u) c++;   // |v| >= 2^65 viewed as bf16 -> impossible for real data
    }
    if (f1) eodd_nz = 1;
    if (c) atomicAdd(&xbig, c);
    __syncthreads();
    if (threadIdx.x == 0) {
        *flagI = (eodd_nz == 0) ? 1 : 0;
        *flagD = (xbig > 8) ? 0 : 1;
    }
}

// ---------------- degree count (in-degree of dst; reads only dst half) ----------------
__global__ void count_deg_kernel(const int* __restrict__ eidx, const int* __restrict__ flagI,
                                 int E, int n, int* __restrict__ cnt) {
    int e = blockIdx.x * blockDim.x + threadIdx.x;
    if (e >= E) return;
    int d;
    if (*flagI) d = (int)((const long long*)eidx)[(long long)E + e];
    else        d = eidx[E + e];
    if (d < 0 || d >= n) return;   // must match scatter's drop condition exactly
    atomicAdd(&cnt[d], 1);
}

__global__ void dinv_kernel(const int* __restrict__ cnt, float* __restrict__ dinv, int n) {
    int i = blockIdx.x * blockDim.x + threadIdx.x;
    if (i < n) dinv[i] = rsqrtf((float)(cnt[i] + 1));
}

// ---------------- exclusive scan of cnt -> row_start ----------------
__global__ void scan_blocks_kernel(const int* __restrict__ cnt, int* __restrict__ row_start,
                                   int* __restrict__ partials, int n) {
    __shared__ int s[256];
    int i = blockIdx.x * 256 + threadIdx.x;
    int v = (i < n) ? cnt[i] : 0;
    s[threadIdx.x] = v;
    __syncthreads();
    for (int off = 1; off < 256; off <<= 1) {
        int t = ((int)threadIdx.x >= off) ? s[threadIdx.x - off] : 0;
        __syncthreads();
        s[threadIdx.x] += t;
        __syncthreads();
    }
    if (i < n) row_start[i] = s[threadIdx.x] - v;
    if (threadIdx.x == 255) partials[blockIdx.x] = s[255];
}

__global__ void scan_partials_kernel(int* __restrict__ partials, int nparts) {
    __shared__ int s[512];
    int v = ((int)threadIdx.x < nparts) ? partials[threadIdx.x] : 0;
    s[threadIdx.x] = v;
    __syncthreads();
    for (int off = 1; off < 512; off <<= 1) {
        int t = ((int)threadIdx.x >= off) ? s[threadIdx.x - off] : 0;
        __syncthreads();
        s[threadIdx.x] += t;
        __syncthreads();
    }
    if ((int)threadIdx.x < nparts) partials[threadIdx.x] = s[threadIdx.x] - v;
}

__global__ void finalize_rows_kernel(int* __restrict__ row_start, const int* __restrict__ partials,
                                     const int* __restrict__ cnt, int* __restrict__ cursor, int n) {
    int i = blockIdx.x * 256 + threadIdx.x;
    if (i < n) {
        int r = row_start[i] + partials[blockIdx.x];
        row_start[i] = r;
        cursor[i] = r;
        if (i == n - 1) row_start[n] = r + cnt[i];
    }
}

// ---------------- CSR scatter: bare 4B src index per edge ----------------
__global__ void scatter_kernel(const int* __restrict__ eidx, const int* __restrict__ flagI,
                               int E, int n, int* __restrict__ cursor, int* __restrict__ csr) {
    int e = blockIdx.x * blockDim.x + threadIdx.x;
    if (e >= E) return;
    int s, d;
    if (*flagI) {
        const long long* p = (const long long*)eidx;
        s = (int)p[e];
        d = (int)p[(long long)E + e];
    } else {
        s = eidx[e];
        d = eidx[E + e];
    }
    if (d < 0 || d >= n) return;             // matches count_deg
    s = min(max(s, 0), n - 1);               // clamp (never drop: keeps rows full)
    int pos = atomicAdd(&cursor[d], 1);
    csr[pos] = s;
}

// ---------------- cast: g0 = dinv .* x  -> packed bf16 rows ----------------
__global__ void cast_g0_kernel(const void* __restrict__ x, uint2* __restrict__ g0,
                               const float* __restrict__ dinv,
                               const int* __restrict__ flagD, int n) {
    int i = blockIdx.x * blockDim.x + threadIdx.x;   // uint2 = 4 features
    int nw2 = n * 32;
    if (i >= nw2) return;
    float w = dinv[i >> 5];
    uint2 o;
    if (*flagD) {
        uint2 v = ((const uint2*)x)[i];
        o.x = pack_bf16(w * bf16_lo(v.x), w * bf16_hi(v.x));
        o.y = pack_bf16(w * bf16_lo(v.y), w * bf16_hi(v.y));
    } else {
        float4 v = ((const float4*)x)[i];
        o.x = pack_bf16(w * v.x, w * v.y);
        o.y = pack_bf16(w * v.z, w * v.w);
    }
    g0[i] = o;
}

// ---------------- cast W -> bf16 (once), b -> fp32 (once) ----------------
__global__ void cast_wb_kernel(const void* __restrict__ W, const void* __restrict__ b,
                               unsigned short* __restrict__ Wb, float* __restrict__ bias_f,
                               const int* __restrict__ flagD) {
    int i = blockIdx.x * 256 + threadIdx.x;
    int bf = *flagD;
    if (i < 128 * 128)
        Wb[i] = bf ? ((const unsigned short*)W)[i] : f32_to_bf16_rne(((const float*)W)[i]);
    if (i < 128)
        bias_f[i] = bf ? bf16_lo((unsigned int)((const unsigned short*)b)[i]) : ((const float*)b)[i];
}

// ---------------- hop: one wave per node, quarter-wave uint4 gathers, no weights ----------------
// lane = 16*e + c. out[i] = scale * (g[i] + sum_s g[s]); scale = di^2 (mid) or di (last).
__global__ __launch_bounds__(256) void hop_kernel(const uint4* __restrict__ hin,
                                                  uint4* __restrict__ hout,
                                                  const int* __restrict__ csr,
                                                  const int* __restrict__ row_start,
                                                  const float* __restrict__ dinv, int n, int last) {
    int gw = (int)((blockIdx.x * 256 + threadIdx.x) >> 6);
    int lane = (int)(threadIdx.x & 63);
    if (gw >= n) return;
    int e = lane >> 4, c = lane & 15;
    float di = dinv[gw];
    float scale = last ? di : di * di;
    int beg = row_start[gw], end = row_start[gw + 1];
    uint4 sv = hin[(size_t)gw * 16 + c];     // self g row
    float a0 = 0.f, a1 = 0.f, a2 = 0.f, a3 = 0.f, a4 = 0.f, a5 = 0.f, a6 = 0.f, a7 = 0.f;
    for (int j = beg + e; j < end; j += 4) {
        int s = csr[j];
        uint4 v = hin[(size_t)s * 16 + c];
        a0 += bf16_lo(v.x); a1 += bf16_hi(v.x);
        a2 += bf16_lo(v.y); a3 += bf16_hi(v.y);
        a4 += bf16_lo(v.z); a5 += bf16_hi(v.z);
        a6 += bf16_lo(v.w); a7 += bf16_hi(v.w);
    }
    a0 += __shfl_xor(a0, 16); a0 += __shfl_xor(a0, 32);
    a1 += __shfl_xor(a1, 16); a1 += __shfl_xor(a1, 32);
    a2 += __shfl_xor(a2, 16); a2 += __shfl_xor(a2, 32);
    a3 += __shfl_xor(a3, 16); a3 += __shfl_xor(a3, 32);
    a4 += __shfl_xor(a4, 16); a4 += __shfl_xor(a4, 32);
    a5 += __shfl_xor(a5, 16); a5 += __shfl_xor(a5, 32);
    a6 += __shfl_xor(a6, 16); a6 += __shfl_xor(a6, 32);
    a7 += __shfl_xor(a7, 16); a7 += __shfl_xor(a7, 32);
    a0 = scale * (a0 + bf16_lo(sv.x)); a1 = scale * (a1 + bf16_hi(sv.x));
    a2 = scale * (a2 + bf16_lo(sv.y)); a3 = scale * (a3 + bf16_hi(sv.y));
    a4 = scale * (a4 + bf16_lo(sv.z)); a5 = scale * (a5 + bf16_hi(sv.z));
    a6 = scale * (a6 + bf16_lo(sv.w)); a7 = scale * (a7 + bf16_hi(sv.w));
    if (e == 0) {
        uint4 o;
        o.x = pack_bf16(a0, a1);
        o.y = pack_bf16(a2, a3);
        o.z = pack_bf16(a4, a5);
        o.w = pack_bf16(a6, a7);
        hout[(size_t)gw * 16 + c] = o;
    }
}

// ---------------- MFMA linear: out = h @ Wb^T + bias ----------------
// 16x16x32 bf16 MFMA. A: lane holds A[m=lane&15][k=q*8+j], q=lane>>4.
// B: lane holds B[k=q*8+j][o=lane&15]. C/D: col=lane&15, row=q*4+reg.
// Grid-stride over 16-row strips; W-frag setup amortized over ~3 strips/wave.
__global__ __launch_bounds__(256, 2) void linear_mfma_kernel(
        const unsigned short* __restrict__ h, const unsigned short* __restrict__ Wb,
        const float* __restrict__ bias_f, void* __restrict__ out,
        const int* __restrict__ flagD, int n) {
    int bf = *flagD;
    int wave = (int)(threadIdx.x >> 6);
    int lane = (int)(threadIdx.x & 63);
    int q = lane >> 4, m16 = lane & 15;

    shortx8 bfrag[8][4];
    float bias[8];
#pragma unroll
    for (int nt = 0; nt < 8; ++nt) {
        int wr = nt * 16 + m16;
#pragma unroll
        for (int t = 0; t < 4; ++t)
            bfrag[nt][t] = *(const shortx8*)&Wb[wr * 128 + t * 32 + q * 8];
        bias[nt] = bias_f[wr];
    }

    int nstrips = (n + 15) / 16;
    int wid = (int)blockIdx.x * 4 + wave;
    int nw = (int)gridDim.x * 4;
    for (int s = wid; s < nstrips; s += nw) {
        int row0 = s * 16;
        int arow = row0 + m16;
        if (arow >= n) arow = n - 1;
        shortx8 afrag[4];
#pragma unroll
        for (int t = 0; t < 4; ++t)
            afrag[t] = *(const shortx8*)&h[(size_t)arow * 128 + t * 32 + q * 8];

        floatx4 acc[8];
#pragma unroll
        for (int nt = 0; nt < 8; ++nt) acc[nt] = (floatx4){0.f, 0.f, 0.f, 0.f};
#pragma unroll
        for (int t = 0; t < 4; ++t)
#pragma unroll
            for (int nt = 0; nt < 8; ++nt)
                acc[nt] = __builtin_amdgcn_mfma_f32_16x16x32_bf16(afrag[t], bfrag[nt][t], acc[nt], 0, 0, 0);

#pragma unroll
        for (int nt = 0; nt < 8; ++nt)
#pragma unroll
            for (int r = 0; r < 4; ++r) {
                int row = row0 + q * 4 + r;
                if (row < n) {
                    float v = acc[nt][r] + bias[nt];
                    size_t oi = (size_t)row * 128 + nt * 16 + m16;
                    if (bf) ((unsigned short*)out)[oi] = f32_to_bf16_rne(v);
                    else    ((float*)out)[oi] = v;
                }
            }
    }
}

extern "C" void kernel_launch(void* const* d_in, const int* in_sizes, int n_in,
                              void* d_out, int out_size, void* d_ws, size_t ws_size,
                              hipStream_t stream) {
    const void* x = d_in[0];
    const int* eidx = (const int*)d_in[1];
    const void* W = d_in[2];
    const void* b = d_in[3];

    int n = in_sizes[0] / DF;   // 100000
    int E = in_sizes[1] / 2;    // 800000

    // workspace carve-up (~30 MB; d_out hosts the second bf16 ping buffer)
    char* ws = (char*)d_ws;
    size_t off = 0;
    auto alloc = [&](size_t bytes) -> void* {
        void* p = ws + off;
        off = (off + bytes + 255) & ~(size_t)255;
        return p;
    };
    unsigned int* hb = (unsigned int*)alloc((size_t)n * 64 * 4);   // bf16 g rows, 25.6MB
    float* dinv      = (float*)alloc((size_t)n * 4);
    int*   cnt       = (int*)alloc((size_t)n * 4);
    int*   row_start = (int*)alloc((size_t)(n + 1) * 4);
    int*   cursor    = (int*)alloc((size_t)n * 4);
    int*   partials  = (int*)alloc(4096);
    int*   flagI     = (int*)alloc(256);
    int*   flagD     = (int*)alloc(256);
    unsigned short* Wb = (unsigned short*)alloc(128 * 128 * 2);    // bf16 W
    float* bias_f    = (float*)alloc(128 * 4);
    int*   csr       = (int*)alloc((size_t)E * 4);                 // bare src index
    unsigned int* xb = (unsigned int*)d_out;                       // bf16 ping buffer in d_out

    hipMemsetAsync(cnt, 0, (size_t)n * 4, stream);

    int enw = 8192; if (2 * E < enw) enw = 2 * E;
    int xnh = 16384; if (n * DF < xnh) xnh = n * DF;
    detect_flags_kernel<<<1, 256, 0, stream>>>((const unsigned int*)eidx, enw,
                                               (const unsigned short*)x, xnh, flagI, flagD);

    int eb = (E + 255) / 256;
    int nb = (n + 255) / 256;   // must be <= 512 for scan_partials
    count_deg_kernel<<<eb, 256, 0, stream>>>(eidx, flagI, E, n, cnt);
    dinv_kernel<<<nb, 256, 0, stream>>>(cnt, dinv, n);
    scan_blocks_kernel<<<nb, 256, 0, stream>>>(cnt, row_start, partials, n);
    scan_partials_kernel<<<1, 512, 0, stream>>>(partials, nb);
    finalize_rows_kernel<<<nb, 256, 0, stream>>>(row_start, partials, cnt, cursor, n);
    scatter_kernel<<<eb, 256, 0, stream>>>(eidx, flagI, E, n, cursor, csr);

    // casts: g0 = dinv.*x -> bf16 rows (in d_out space); W -> bf16, b -> fp32
    int nw2 = n * 32;  // uint2 count
    cast_g0_kernel<<<(nw2 + 255) / 256, 256, 0, stream>>>(x, (uint2*)xb, dinv, flagD, n);
    cast_wb_kernel<<<64, 256, 0, stream>>>(W, b, Wb, bias_f, flagD);

    // hops ping-pong: g0(xb=d_out) -> hb -> xb -> hb; last hop emits h3 = di*(...)
    int hb_grid = (n + 3) / 4;
    hop_kernel<<<hb_grid, 256, 0, stream>>>((const uint4*)xb, (uint4*)hb, csr, row_start, dinv, n, 0);
    hop_kernel<<<hb_grid, 256, 0, stream>>>((const uint4*)hb, (uint4*)xb, csr, row_start, dinv, n, 0);
    hop_kernel<<<hb_grid, 256, 0, stream>>>((const uint4*)xb, (uint4*)hb, csr, row_start, dinv, n, 1);

    // linear: reads h3 (hb), writes full d_out (xb region is dead)
    int nstrips = (n + 15) / 16;
    int lgrid = 512; if ((nstrips + 3) / 4 < lgrid) lgrid = (nstrips + 3) / 4;
    linear_mfma_kernel<<<lgrid, 256, 0, stream>>>(
        (const unsigned short*)hb, Wb, bias_f, d_out, flagD, n);
}